// Round 7
// baseline (291.243 us; speedup 1.0000x reference)
//
#include <hip/hip_runtime.h>
#include <hip/hip_bf16.h>
#include <type_traits>

typedef __bf16 bf16;
typedef __bf16 bf16x2 __attribute__((ext_vector_type(2)));
typedef __bf16 bf16x4 __attribute__((ext_vector_type(4)));
typedef __bf16 bf16x8 __attribute__((ext_vector_type(8)));
typedef float f32x4 __attribute__((ext_vector_type(4)));

#define AS1 __attribute__((address_space(1)))
#define AS3 __attribute__((address_space(3)))

// 0.125 (1/sqrt(64)) * log2(e): folded into Q so attn scores are log2-domain.
#define KAPPA 0.180336880111f

__device__ __forceinline__ void load_lds16(const void* g, void* l) {
  __builtin_amdgcn_global_load_lds((AS1 void*)g, (AS3 void*)l, 16, 0, 0);
}
__device__ __forceinline__ float exp2_fast(float x) {
  return __builtin_amdgcn_exp2f(x);
}

// ---------------------------------------------------------------------------
// fp32->bf16 conversions. x -> row-major xb (4 elems/thread, unchanged).
// Weights -> MFMA-FRAGMENT-SHUFFLED layout (8 elems/thread):
//   element (n,k) -> byte ((n>>6)*64 + (k>>5))*4096   [64x32 block]
//                  + ((n>>4)&3)*1024                   [frag j]
//                  + ((n&15) | (((k>>3)&3)<<4))*16     [lane]
//                  + (k&7)*2                           [elem in bf16x8]
// so a wave loads frag j of block (n0,k0) with ONE coalesced
// global_load_dwordx4 at blk*4096 + j*1024 + lane*16 -- B operand goes
// DIRECTLY to registers in the GEMMs, never through LDS.
// ---------------------------------------------------------------------------
__global__ void f2b_all(const float* __restrict__ x, const float* __restrict__ wq,
                        const float* __restrict__ wk, const float* __restrict__ wv,
                        const float* __restrict__ wo, bf16* __restrict__ xb,
                        bf16* __restrict__ wqkv, bf16* __restrict__ wob) {
  int bid = blockIdx.x;
  if (bid < 8192) {  // x: row-major, 4 f32/thread
    int i = (bid * 256 + threadIdx.x) * 4;
    float4 v = *(const float4*)(x + i);
    bf16x4 o = {(bf16)v.x, (bf16)v.y, (bf16)v.z, (bf16)v.w};
    *(bf16x4*)(xb + i) = o;
    return;
  }
  const float* src;
  bf16* dst;
  int off;
  if (bid < 10240) { src = wq; dst = wqkv; off = bid - 8192; }
  else if (bid < 10752) { src = wk; dst = wqkv + 4194304; off = bid - 10240; }
  else if (bid < 11264) { src = wv; dst = wqkv + 5242880; off = bid - 10752; }
  else { src = wo; dst = wob; off = bid - 11264; }
  int i = (off * 256 + threadIdx.x) * 8;
  int n = i >> 11, k = i & 2047;
  float4 v0 = *(const float4*)(src + (size_t)n * 2048 + k);
  float4 v1 = *(const float4*)(src + (size_t)n * 2048 + k + 4);
  bf16x8 o = {(bf16)v0.x, (bf16)v0.y, (bf16)v0.z, (bf16)v0.w,
              (bf16)v1.x, (bf16)v1.y, (bf16)v1.z, (bf16)v1.w};
  size_t dstb = ((size_t)((n >> 6) * 64 + (k >> 5))) * 4096 +
                (size_t)((n >> 4) & 3) * 1024 +
                (size_t)((n & 15) | (((k >> 3) & 3) << 4)) * 16;
  *(bf16x8*)((char*)dst + dstb) = o;
}

// ---------------------------------------------------------------------------
// Fused QKV projection GEMM. Round-6 arithmetic: at 12 waves/CU the old
// kernel read 96KB + wrote 24KB LDS per K-tile vs 323cy of MFMA -- LDS-BW
// bound ~4x over. Fix: B operand (weights, fragment-shuffled by f2b_all)
// loads DIRECTLY to registers (4 coalesced global_load_dwordx4/wave/tile,
// reg-alternated one tile ahead). Only A goes through LDS (rows shared by
// 2 waves; B rows were never shared -- staging B was pure LDS overhead).
// LDS/CU/tile: 120KB -> 72KB; ds_reads/wave 8 -> 4.
//   128x128 tile, 4 waves, BK=32, A: 3-slot ring (24 KB), stage distance 2,
//   grid 24x32 = 768 = 3 blocks/CU, 12 waves/CU.
// vmcnt ledger (VMEM FIFO): iter tk issues [stageA(tk+2):2, loadB(tk+1):4].
//   Before MFMA(tk): need B(tk) (issued iter tk-1) -> remaining after it =
//   A(tk+2)+B(tk+1) = 6 -> vmcnt(6). Retires A(tk+1) (issued before B(tk))
//   as a side effect -> next iter's ds_read safe after barrier. Tail:
//   tk==62 -> vmcnt(4), tk==63 -> vmcnt(0). lgkm(0) same wait (A ds_reads).
// A slot hazard: stage(tk+2) -> slot (tk+2)%3 overwrites tile tk-1, whose
//   reads drained (lgkm0) before iter tk-1's end barrier.
// A LDS swizzle: seg ^= (ro>>1)&3 on global source; read seg offset is the
//   per-thread constant (qd^((ln>>1)&3))*16. VERIFIED conflict-free (0).
// Epilogue (round-0 verified): bn<16 -> Q+rope*KAPPA; 16-19 -> K+rope;
//   20-23 -> V^T.
// ---------------------------------------------------------------------------
__global__ __launch_bounds__(256, 3) void gemm_qkv(const bf16* __restrict__ A,
                                                   const bf16* __restrict__ Bw,
                                                   const float* __restrict__ fc,
                                                   const float* __restrict__ fs,
                                                   bf16* __restrict__ Qro,
                                                   bf16* __restrict__ Kro,
                                                   bf16* __restrict__ Vt) {
  const int K = 2048;
  __shared__ bf16 As[3][128][32];  // 24 KB ring
  const int t = threadIdx.x;
  const int wave = t >> 6, lane = t & 63, qd = lane >> 4, ln = lane & 15;
  const int wm = (wave >> 1) * 64;
  const int wn = (wave & 1) * 64;
  const int bn = blockIdx.x;  // 0..23 (Q:0-15, K:16-19, V:20-23)
  const size_t bm = (size_t)blockIdx.y * 128;

  const bf16* Ab = A + bm * (size_t)K;
  const int n0 = bn * 2 + (wn >> 6);
  // B fragment base for this wave+lane: blk (n0,tk) at n0*64*4096 + tk*4096.
  const char* Bb = (const char*)Bw + (size_t)n0 * 262144 + (size_t)lane * 16;

  auto stage = [&](int tk, int slot) {
#pragma unroll
    for (int sub = 0; sub < 2; sub++) {
      int e = sub * 256 + t;
      int ro = e >> 2, gs = (e & 3) ^ ((ro >> 1) & 3);
      load_lds16(Ab + (size_t)ro * K + tk * 32 + gs * 8,
                 (char*)As + slot * 8192 + sub * 4096 + wave * 1024);
    }
  };

  f32x4 acc[4][4] = {};
  const int segoff = (qd ^ ((ln >> 1) & 3)) << 4;
  bf16x8 b0[4], b1[4];

  // Prologue: B(0) first, then A(0),A(1) -> need B0+A0: vmcnt(2) leaves A1.
#pragma unroll
  for (int j = 0; j < 4; j++)
    b0[j] = *(const bf16x8*)(Bb + (size_t)j * 1024);
  stage(0, 0);
  stage(1, 1);
  asm volatile("s_waitcnt vmcnt(2)" ::: "memory");
  __builtin_amdgcn_s_barrier();

  // One iter: stage A(tk+2), load B(tk+1)->nb, ds_read A(tk), wait, MFMA(cb).
  auto step = [&](int tk, bf16x8 (&cb)[4], bf16x8 (&nb)[4]) {
    if (tk < 62) stage(tk + 2, (tk + 2) % 3);
    if (tk < 63) {
#pragma unroll
      for (int j = 0; j < 4; j++)
        nb[j] = *(const bf16x8*)(Bb + (size_t)(tk + 1) * 4096 + j * 1024);
    }
    const char* Asl = (const char*)As + (tk % 3) * 8192;
    bf16x8 af[4];
#pragma unroll
    for (int i = 0; i < 4; i++)
      af[i] = *(const bf16x8*)(Asl + (wm + i * 16 + ln) * 64 + segoff);
    if (tk <= 61) asm volatile("s_waitcnt lgkmcnt(0) vmcnt(6)" ::: "memory");
    else if (tk == 62) asm volatile("s_waitcnt lgkmcnt(0) vmcnt(4)" ::: "memory");
    else asm volatile("s_waitcnt lgkmcnt(0) vmcnt(0)" ::: "memory");
    __builtin_amdgcn_sched_barrier(0);
    __builtin_amdgcn_s_setprio(1);
#pragma unroll
    for (int i = 0; i < 4; i++)
#pragma unroll
      for (int j = 0; j < 4; j++)
        acc[i][j] = __builtin_amdgcn_mfma_f32_16x16x32_bf16(af[i], cb[j],
                                                            acc[i][j], 0, 0, 0);
    __builtin_amdgcn_s_setprio(0);
    if (tk < 63) __builtin_amdgcn_s_barrier();
  };

  for (int tk = 0; tk < 64; tk += 2) {
    step(tk, b0, b1);
    step(tk + 1, b1, b0);
  }

  // ---- epilogue (round-0 verified) ----
  const int b = (int)(bm >> 11);
  const int sb = (int)(bm & 2047) + wm;
  const bool odd = ln & 1;

  if (bn < 20) {  // Q or K: rope, head-major output
    const bool isQ = bn < 16;
    const float kap = isQ ? KAPPA : 1.0f;
    const int hh = isQ ? (bn * 2 + (wn >> 6)) : ((bn - 16) * 2 + (wn >> 6));
    bf16* dst = isQ ? (Qro + ((size_t)(b * 32 + hh) * 2048) * 64)
                    : (Kro + ((size_t)(b * 8 + hh) * 2048) * 64);
#pragma unroll
    for (int i = 0; i < 4; i++) {
#pragma unroll
      for (int j = 0; j < 4; j++) {
        const int d = j * 16 + ln;
        const int i_f = d >> 1;
#pragma unroll
        for (int r = 0; r < 4; r++) {
          int s = sb + i * 16 + qd * 4 + r;
          float v = acc[i][j][r];
          float p = __shfl_xor(v, 1);
          float cv = fc[s * 32 + i_f] * kap;
          float sv = fs[s * 32 + i_f] * kap;
          float o = odd ? (p * sv + v * cv) : (v * cv - p * sv);
          dst[(size_t)s * 64 + d] = (bf16)o;
        }
      }
    }
  } else {  // V: write transposed (B,8,64,S)
    const int kh = (bn - 20) * 2 + (wn >> 6);
#pragma unroll
    for (int i = 0; i < 4; i++)
#pragma unroll
      for (int j = 0; j < 4; j++) {
        const int d = j * 16 + ln;
        int s = sb + i * 16 + qd * 4;
        bf16x4 ov = {(bf16)acc[i][j][0], (bf16)acc[i][j][1],
                     (bf16)acc[i][j][2], (bf16)acc[i][j][3]};
        *(bf16x4*)&Vt[((size_t)(b * 8 + kh) * 64 + d) * 2048 + s] = ov;
      }
  }
}

// ---------------------------------------------------------------------------
// Output projection GEMM: identical structure (shuffled wob, B direct to
// registers, A via 3-slot LDS ring). Grid (16,32) = 512 = 2 blocks/CU.
// ---------------------------------------------------------------------------
__global__ __launch_bounds__(256, 2) void gemm_bt(const bf16* __restrict__ A,
                                                  const bf16* __restrict__ Bw,
                                                  float* __restrict__ C) {
  const int K = 2048, N = 2048;
  __shared__ bf16 As[3][128][32];
  const int t = threadIdx.x;
  const int wave = t >> 6, lane = t & 63, qd = lane >> 4, ln = lane & 15;
  const int wm = (wave >> 1) * 64;
  const int wn = (wave & 1) * 64;
  const size_t bm = (size_t)blockIdx.y * 128;
  const size_t bn = (size_t)blockIdx.x * 128;

  const bf16* Ab = A + bm * (size_t)K;
  const int n0 = (int)(bn >> 6) + (wn >> 6);
  const char* Bb = (const char*)Bw + (size_t)n0 * 262144 + (size_t)lane * 16;

  auto stage = [&](int tk, int slot) {
#pragma unroll
    for (int sub = 0; sub < 2; sub++) {
      int e = sub * 256 + t;
      int ro = e >> 2, gs = (e & 3) ^ ((ro >> 1) & 3);
      load_lds16(Ab + (size_t)ro * K + tk * 32 + gs * 8,
                 (char*)As + slot * 8192 + sub * 4096 + wave * 1024);
    }
  };

  f32x4 acc[4][4] = {};
  const int segoff = (qd ^ ((ln >> 1) & 3)) << 4;
  bf16x8 b0[4], b1[4];

#pragma unroll
  for (int j = 0; j < 4; j++)
    b0[j] = *(const bf16x8*)(Bb + (size_t)j * 1024);
  stage(0, 0);
  stage(1, 1);
  asm volatile("s_waitcnt vmcnt(2)" ::: "memory");
  __builtin_amdgcn_s_barrier();

  auto step = [&](int tk, bf16x8 (&cb)[4], bf16x8 (&nb)[4]) {
    if (tk < 62) stage(tk + 2, (tk + 2) % 3);
    if (tk < 63) {
#pragma unroll
      for (int j = 0; j < 4; j++)
        nb[j] = *(const bf16x8*)(Bb + (size_t)(tk + 1) * 4096 + j * 1024);
    }
    const char* Asl = (const char*)As + (tk % 3) * 8192;
    bf16x8 af[4];
#pragma unroll
    for (int i = 0; i < 4; i++)
      af[i] = *(const bf16x8*)(Asl + (wm + i * 16 + ln) * 64 + segoff);
    if (tk <= 61) asm volatile("s_waitcnt lgkmcnt(0) vmcnt(6)" ::: "memory");
    else if (tk == 62) asm volatile("s_waitcnt lgkmcnt(0) vmcnt(4)" ::: "memory");
    else asm volatile("s_waitcnt lgkmcnt(0) vmcnt(0)" ::: "memory");
    __builtin_amdgcn_sched_barrier(0);
    __builtin_amdgcn_s_setprio(1);
#pragma unroll
    for (int i = 0; i < 4; i++)
#pragma unroll
      for (int j = 0; j < 4; j++)
        acc[i][j] = __builtin_amdgcn_mfma_f32_16x16x32_bf16(af[i], cb[j],
                                                            acc[i][j], 0, 0, 0);
    __builtin_amdgcn_s_setprio(0);
    if (tk < 63) __builtin_amdgcn_s_barrier();
  };

  for (int tk = 0; tk < 64; tk += 2) {
    step(tk, b0, b1);
    step(tk + 1, b1, b0);
  }

#pragma unroll
  for (int i = 0; i < 4; i++)
#pragma unroll
    for (int j = 0; j < 4; j++)
#pragma unroll
      for (int r = 0; r < 4; r++) {
        size_t row = bm + wm + i * 16 + qd * 4 + r;
        size_t col = bn + wn + j * 16 + ln;
        C[row * N + col] = acc[i][j][r];
      }
}

// ---------------------------------------------------------------------------
// Flash attention (unchanged from round 5): S^T formulation, causal,
// log2-domain fixed-point softmax p = 2^(s-16). Q fragments in registers;
// K/V 2-slot ring staged at top of iteration; one __syncthreads per tile.
// Q:(B,32,S,64)  K:(B,8,S,64)  Vt:(B,8,64,S)  ->  O:(B,S,32,64)
// ---------------------------------------------------------------------------
__global__ __launch_bounds__(256, 3) void attn_fwd(const bf16* __restrict__ Q,
                                                   const bf16* __restrict__ Kg,
                                                   const bf16* __restrict__ Vg,
                                                   bf16* __restrict__ O) {
  __shared__ bf16 Ks[2][64][64];  // 16 KB ring
  __shared__ bf16 Vs[2][64][64];  // 16 KB ring, [d][k]
  __shared__ bf16 Ps[128][64];    // [q][k], swizzled
  const int t = threadIdx.x;
  const int wave = t >> 6, lane = t & 63, qd = lane >> 4, ln = lane & 15;
  const int bid = blockIdx.x;
  const int qt = 15 - (bid >> 6);  // longest blocks dispatch first
  const int bh = bid & 63;
  const int b = bh >> 5, h = bh & 31, kh = h >> 2;
  const bf16* Qb = Q + ((size_t)(b * 32 + h) * 2048 + qt * 128) * 64;  // contiguous
  const bf16* Kb = Kg + (size_t)(b * 8 + kh) * 2048 * 64;              // contiguous
  const bf16* Vb = Vg + (size_t)(b * 8 + kh) * 64 * 2048;              // row stride 2048
  char* PsB = (char*)Ps;

  bf16x8 qf[2][2];
#pragma unroll
  for (int kk = 0; kk < 2; kk++)
#pragma unroll
    for (int mi = 0; mi < 2; mi++)
      qf[kk][mi] = *(const bf16x8*)(Qb + (wave * 32 + mi * 16 + ln) * 64 +
                                    (kk * 4 + qd) * 8);

  auto stageKV = [&](int kb, int buf) {
#pragma unroll
    for (int i = 0; i < 2; i++) {
      int e = i * 256 + t;
      int row = e >> 3, sg = (e & 7) ^ (row & 7);
      load_lds16(Kb + (size_t)(kb * 64 + row) * 64 + sg * 8,
                 (char*)Ks + buf * 8192 + i * 4096 + wave * 1024);
      load_lds16(Vb + (size_t)row * 2048 + kb * 64 + sg * 8,
                 (char*)Vs + buf * 8192 + i * 4096 + wave * 1024);
    }
  };

  f32x4 o_acc[4][2] = {};
  float l_st[2] = {0.f, 0.f};
  const int q0 = qt * 128 + wave * 32;
  const int nkb = 2 * qt + 2;

  stageKV(0, 0);
  __syncthreads();  // K0/V0 landed (vmcnt drain)

  for (int kb = 0; kb < nkb; kb++) {
    const int cur = kb & 1;
    if (kb + 1 < nkb) stageKV(kb + 1, cur ^ 1);
    const char* Ksl = (const char*)Ks + cur * 8192;
    const char* Vsl = (const char*)Vs + cur * 8192;

    // S^T = K*Q^T
    f32x4 s_acc[4][2] = {};
#pragma unroll
    for (int kk = 0; kk < 2; kk++) {
      bf16x8 ak[4];
#pragma unroll
      for (int j = 0; j < 4; j++) {
        int row = j * 16 + ln;
        int ph = (kk * 4 + qd) ^ (ln & 7);
        ak[j] = *(const bf16x8*)(Ksl + row * 128 + ph * 16);
      }
#pragma unroll
      for (int j = 0; j < 4; j++)
#pragma unroll
        for (int mi = 0; mi < 2; mi++)
          s_acc[j][mi] = __builtin_amdgcn_mfma_f32_16x16x32_bf16(
              ak[j], qf[kk][mi], s_acc[j][mi], 0, 0, 0);
    }

    // fixed-point softmax: p = 2^(s-16); masked -> exact 0
    auto smax = [&](auto maskc) {
      constexpr bool MASK = decltype(maskc)::value;
#pragma unroll
      for (int mi = 0; mi < 2; mi++) {
        const int qv = q0 + mi * 16 + ln;
        const int prow = wave * 32 + mi * 16 + ln;
        float rs = 0.f;
#pragma unroll
        for (int j = 0; j < 4; j++) {
          bf16x4 pk;
#pragma unroll
          for (int r = 0; r < 4; r++) {
            float s = s_acc[j][mi][r];
            if (MASK) {
              int k_glob = kb * 64 + j * 16 + qd * 4 + r;
              if (k_glob > qv) s = -1e5f;
            }
            float pv = exp2_fast(s - 16.f);
            rs += pv;
            pk[r] = (bf16)pv;
          }
          int ps = (j * 2 + (qd >> 1)) ^ (ln & 7);
          *(bf16x4*)(PsB + prow * 128 + ps * 16 + (qd & 1) * 8) = pk;
        }
        l_st[mi] += rs;
      }
    };
    if (kb * 64 + 63 > q0) smax(std::true_type{});
    else smax(std::false_type{});

    // O^T += V^T * P^T  (Ps wave-private; lgkmcnt orders write->read)
#pragma unroll
    for (int kk = 0; kk < 2; kk++) {
      bf16x8 av[4], bp[2];
#pragma unroll
      for (int dj = 0; dj < 4; dj++) {
        int row = dj * 16 + ln;
        int ph = (kk * 4 + qd) ^ (ln & 7);
        av[dj] = *(const bf16x8*)(Vsl + row * 128 + ph * 16);
      }
#pragma unroll
      for (int mi = 0; mi < 2; mi++) {
        int prow = wave * 32 + mi * 16 + ln;
        int ph = (kk * 4 + qd) ^ (ln & 7);
        bp[mi] = *(const bf16x8*)(PsB + prow * 128 + ph * 16);
      }
#pragma unroll
      for (int dj = 0; dj < 4; dj++)
#pragma unroll
        for (int mi = 0; mi < 2; mi++)
          o_acc[dj][mi] = __builtin_amdgcn_mfma_f32_16x16x32_bf16(
              av[dj], bp[mi], o_acc[dj][mi], 0, 0, 0);
    }

    __syncthreads();
  }

  // epilogue: reduce l across quads (each quad summed a disjoint k-subset)
#pragma unroll
  for (int mi = 0; mi < 2; mi++) {
    float lt = l_st[mi];
    lt += __shfl_xor(lt, 16);
    lt += __shfl_xor(lt, 32);
    float inv = 1.f / lt;
    int q_idx = qt * 128 + wave * 32 + mi * 16 + ln;
#pragma unroll
    for (int dj = 0; dj < 4; dj++) {
      bf16x4 ov;
#pragma unroll
      for (int r = 0; r < 4; r++) ov[r] = (bf16)(o_acc[dj][mi][r] * inv);
      *(bf16x4*)&O[((size_t)(b * 2048 + q_idx) * 32 + h) * 64 + dj * 16 + qd * 4] = ov;
    }
  }
}

// ---------------------------------------------------------------------------
extern "C" void kernel_launch(void* const* d_in, const int* in_sizes, int n_in,
                              void* d_out, int out_size, void* d_ws,
                              size_t ws_size, hipStream_t stream) {
  const float* x = (const float*)d_in[0];
  const float* fc = (const float*)d_in[1];
  const float* fs = (const float*)d_in[2];
  const float* wq = (const float*)d_in[3];
  const float* wk = (const float*)d_in[4];
  const float* wv = (const float*)d_in[5];
  const float* wo = (const float*)d_in[6];
  float* out = (float*)d_out;

  char* ws = (char*)d_ws;
  const size_t MB = (size_t)1 << 20;
  bf16* xb   = (bf16*)(ws + 0 * MB);   // 16 MB (4096,2048) row-major
  bf16* wqkv = (bf16*)(ws + 16 * MB);  // 12 MB fragment-shuffled
  bf16* wob  = (bf16*)(ws + 28 * MB);  // 8 MB fragment-shuffled
  bf16* Qro  = (bf16*)(ws + 36 * MB);  // 16 MB (B,32,S,64), roped*KAPPA
  bf16* Kro  = (bf16*)(ws + 52 * MB);  // 4 MB  (B,8,S,64), roped
  bf16* Vt   = (bf16*)(ws + 56 * MB);  // 4 MB  (B,8,64,S)
  bf16* Oa   = (bf16*)(ws + 60 * MB);  // 16 MB (B,S,32,64)

  dim3 blk(256);
  f2b_all<<<13312, blk, 0, stream>>>(x, wq, wk, wv, wo, xb, wqkv, wob);
  gemm_qkv<<<dim3(24, 32), blk, 0, stream>>>(xb, wqkv, fc, fs, Qro, Kro, Vt);
  attn_fwd<<<1024, blk, 0, stream>>>(Qro, Kro, Vt, Oa);
  gemm_bt<<<dim3(16, 32), blk, 0, stream>>>(Oa, wob, out);
}

// Round 8
// 271.931 us; speedup vs baseline: 1.0710x; 1.0710x over previous
//
#include <hip/hip_runtime.h>
#include <hip/hip_bf16.h>
#include <type_traits>

typedef __bf16 bf16;
typedef __bf16 bf16x2 __attribute__((ext_vector_type(2)));
typedef __bf16 bf16x4 __attribute__((ext_vector_type(4)));
typedef __bf16 bf16x8 __attribute__((ext_vector_type(8)));
typedef float f32x4 __attribute__((ext_vector_type(4)));

#define AS1 __attribute__((address_space(1)))
#define AS3 __attribute__((address_space(3)))

// 0.125 (1/sqrt(64)) * log2(e): folded into Q so attn scores are log2-domain.
#define KAPPA 0.180336880111f

__device__ __forceinline__ void load_lds16(const void* g, void* l) {
  __builtin_amdgcn_global_load_lds((AS1 void*)g, (AS3 void*)l, 16, 0, 0);
}
__device__ __forceinline__ float exp2_fast(float x) {
  return __builtin_amdgcn_exp2f(x);
}

// ---------------------------------------------------------------------------
// fp32->bf16. x -> row-major (4 elems/thread). Weights -> MFMA-fragment-
// shuffled layout: element (n,k) -> byte ((n>>6)*64+(k>>5))*4096 +
// ((n>>4)&3)*1024 + ((n&15)|(((k>>3)&3)<<4))*16 + (k&7)*2, so a GEMM wave
// loads frag j of block (n0,tk) with one coalesced dwordx4 at
// blk*4096 + j*1024 + lane*16. One 256-thr block per 64x32 weight block:
// thread t (j=t>>6, l=t&63) handles row n0+16j+(l&15), k kblk*32+(l>>4)*8..+7
// -> writes are 1KB-contiguous per wave (r7's 64B scattered writes RMW'd),
// reads are 16 full 128B lines per wave.
// ---------------------------------------------------------------------------
__global__ void f2b_all(const float* __restrict__ x, const float* __restrict__ wq,
                        const float* __restrict__ wk, const float* __restrict__ wv,
                        const float* __restrict__ wo, bf16* __restrict__ xb,
                        bf16* __restrict__ wqkv, bf16* __restrict__ wob) {
  int bid = blockIdx.x;
  if (bid < 8192) {  // x: row-major, 4 f32/thread
    int i = (bid * 256 + threadIdx.x) * 4;
    float4 v = *(const float4*)(x + i);
    bf16x4 o = {(bf16)v.x, (bf16)v.y, (bf16)v.z, (bf16)v.w};
    *(bf16x4*)(xb + i) = o;
    return;
  }
  int bid2 = bid - 8192;
  const float* src;
  bf16* dst;
  int nblk, kblk, nb;
  if (bid2 < 3072) {  // wqkv: 48 nblks x 64 kblks
    nblk = bid2 >> 6;
    kblk = bid2 & 63;
    int n0 = nblk * 64;
    if (n0 < 2048) { src = wq; nb = n0; }
    else if (n0 < 2560) { src = wk; nb = n0 - 2048; }
    else { src = wv; nb = n0 - 2560; }
    dst = wqkv;
  } else {  // wob: 32 nblks x 64 kblks
    int bid3 = bid2 - 3072;
    nblk = bid3 >> 6;
    kblk = bid3 & 63;
    src = wo;
    nb = nblk * 64;
    dst = wob;
  }
  const int t = threadIdx.x, j = t >> 6, l = t & 63;
  const int n = nb + j * 16 + (l & 15);
  const int k = kblk * 32 + (l >> 4) * 8;
  float4 v0 = *(const float4*)(src + (size_t)n * 2048 + k);
  float4 v1 = *(const float4*)(src + (size_t)n * 2048 + k + 4);
  bf16x8 o = {(bf16)v0.x, (bf16)v0.y, (bf16)v0.z, (bf16)v0.w,
              (bf16)v1.x, (bf16)v1.y, (bf16)v1.z, (bf16)v1.w};
  *(bf16x8*)((char*)dst + ((size_t)(nblk * 64 + kblk)) * 4096 + j * 1024 +
             l * 16) = o;
}

// ---------------------------------------------------------------------------
// Fused QKV projection GEMM (r7 body, verified). New: XCD-locality swizzle.
// r7 falsified LDS-BW as the limiter (24K LDS, same 70us). Remaining
// accounting: L2-visible reads = B x32 bm-blocks (786MB) + A x24 bn-blocks
// (393MB) ~= 1.2GB/70us = 17 TB/s with ZERO per-XCD reuse under round-robin
// dispatch (consecutive blocks -> different XCDs). Swizzle: 1-D grid 768
// (all resident), XCD c = wg%8 gets bn {3c,3c+1,3c+2} x all bm -> its 3
// B col-panels (1.5MB) L2-resident for the whole kernel; A panels shared by
// the 3 co-XCD consumers. External traffic ~1.2GB -> ~140MB.
//   128x128 tile, 4 waves, BK=32, A: 3-slot LDS ring (24KB), B direct to
//   registers from fragment-shuffled layout (4 coalesced dwordx4/wave/tile,
//   alternated one tile ahead). 3 blocks/CU, 12 waves/CU.
// vmcnt ledger: iter tk issues [stageA(tk+2):2, loadB(tk+1):4]; before
//   MFMA(tk) need B(tk) -> vmcnt(6) (retires A(tk+1) too). Tail 62->4, 63->0.
// A slot hazard: stage(tk+2) overwrites tile tk-1's slot; its reads drained
//   (lgkm0) before iter tk-1's end barrier.
// A swizzle seg^=(ro>>1)&3 on global source; read seg offset constant;
//   VERIFIED conflict-free (0 in rocprof).
// Epilogue (round-0 verified): bn<16 Q+rope*KAPPA; 16-19 K+rope; 20-23 V^T.
// ---------------------------------------------------------------------------
__global__ __launch_bounds__(256, 3) void gemm_qkv(const bf16* __restrict__ A,
                                                   const bf16* __restrict__ Bw,
                                                   const float* __restrict__ fc,
                                                   const float* __restrict__ fs,
                                                   bf16* __restrict__ Qro,
                                                   bf16* __restrict__ Kro,
                                                   bf16* __restrict__ Vt) {
  const int K = 2048;
  __shared__ bf16 As[3][128][32];  // 24 KB ring
  const int t = threadIdx.x;
  const int wave = t >> 6, lane = t & 63, qd = lane >> 4, ln = lane & 15;
  const int wm = (wave >> 1) * 64;
  const int wn = (wave & 1) * 64;
  // XCD swizzle: wg%8 = XCD (round-robin dispatch); each XCD owns a
  // contiguous 96-block chunk = 3 bn x 32 bm. Bijective (768 = 8*96).
  const int wg = blockIdx.x;
  const int swz = (wg & 7) * 96 + (wg >> 3);
  const int bn = swz >> 5;                    // 0..23 (Q:0-15,K:16-19,V:20-23)
  const size_t bm = (size_t)(swz & 31) * 128;

  const bf16* Ab = A + bm * (size_t)K;
  const int n0 = bn * 2 + (wn >> 6);
  const char* Bb = (const char*)Bw + (size_t)n0 * 262144 + (size_t)lane * 16;

  auto stage = [&](int tk, int slot) {
#pragma unroll
    for (int sub = 0; sub < 2; sub++) {
      int e = sub * 256 + t;
      int ro = e >> 2, gs = (e & 3) ^ ((ro >> 1) & 3);
      load_lds16(Ab + (size_t)ro * K + tk * 32 + gs * 8,
                 (char*)As + slot * 8192 + sub * 4096 + wave * 1024);
    }
  };

  f32x4 acc[4][4] = {};
  const int segoff = (qd ^ ((ln >> 1) & 3)) << 4;
  bf16x8 b0[4], b1[4];

  // Prologue: B(0) first, then A(0),A(1) -> need B0+A0: vmcnt(2) leaves A1.
#pragma unroll
  for (int j = 0; j < 4; j++)
    b0[j] = *(const bf16x8*)(Bb + (size_t)j * 1024);
  stage(0, 0);
  stage(1, 1);
  asm volatile("s_waitcnt vmcnt(2)" ::: "memory");
  __builtin_amdgcn_s_barrier();

  auto step = [&](int tk, bf16x8 (&cb)[4], bf16x8 (&nb)[4]) {
    if (tk < 62) stage(tk + 2, (tk + 2) % 3);
    if (tk < 63) {
#pragma unroll
      for (int j = 0; j < 4; j++)
        nb[j] = *(const bf16x8*)(Bb + (size_t)(tk + 1) * 4096 + j * 1024);
    }
    const char* Asl = (const char*)As + (tk % 3) * 8192;
    bf16x8 af[4];
#pragma unroll
    for (int i = 0; i < 4; i++)
      af[i] = *(const bf16x8*)(Asl + (wm + i * 16 + ln) * 64 + segoff);
    if (tk <= 61) asm volatile("s_waitcnt lgkmcnt(0) vmcnt(6)" ::: "memory");
    else if (tk == 62) asm volatile("s_waitcnt lgkmcnt(0) vmcnt(4)" ::: "memory");
    else asm volatile("s_waitcnt lgkmcnt(0) vmcnt(0)" ::: "memory");
    __builtin_amdgcn_sched_barrier(0);
    __builtin_amdgcn_s_setprio(1);
#pragma unroll
    for (int i = 0; i < 4; i++)
#pragma unroll
      for (int j = 0; j < 4; j++)
        acc[i][j] = __builtin_amdgcn_mfma_f32_16x16x32_bf16(af[i], cb[j],
                                                            acc[i][j], 0, 0, 0);
    __builtin_amdgcn_s_setprio(0);
    if (tk < 63) __builtin_amdgcn_s_barrier();
  };

  for (int tk = 0; tk < 64; tk += 2) {
    step(tk, b0, b1);
    step(tk + 1, b1, b0);
  }

  // ---- epilogue (round-0 verified) ----
  const int b = (int)(bm >> 11);
  const int sb = (int)(bm & 2047) + wm;
  const bool odd = ln & 1;

  if (bn < 20) {  // Q or K: rope, head-major output
    const bool isQ = bn < 16;
    const float kap = isQ ? KAPPA : 1.0f;
    const int hh = isQ ? (bn * 2 + (wn >> 6)) : ((bn - 16) * 2 + (wn >> 6));
    bf16* dst = isQ ? (Qro + ((size_t)(b * 32 + hh) * 2048) * 64)
                    : (Kro + ((size_t)(b * 8 + hh) * 2048) * 64);
#pragma unroll
    for (int i = 0; i < 4; i++) {
#pragma unroll
      for (int j = 0; j < 4; j++) {
        const int d = j * 16 + ln;
        const int i_f = d >> 1;
#pragma unroll
        for (int r = 0; r < 4; r++) {
          int s = sb + i * 16 + qd * 4 + r;
          float v = acc[i][j][r];
          float p = __shfl_xor(v, 1);
          float cv = fc[s * 32 + i_f] * kap;
          float sv = fs[s * 32 + i_f] * kap;
          float o = odd ? (p * sv + v * cv) : (v * cv - p * sv);
          dst[(size_t)s * 64 + d] = (bf16)o;
        }
      }
    }
  } else {  // V: write transposed (B,8,64,S)
    const int kh = (bn - 20) * 2 + (wn >> 6);
#pragma unroll
    for (int i = 0; i < 4; i++)
#pragma unroll
      for (int j = 0; j < 4; j++) {
        const int d = j * 16 + ln;
        int s = sb + i * 16 + qd * 4;
        bf16x4 ov = {(bf16)acc[i][j][0], (bf16)acc[i][j][1],
                     (bf16)acc[i][j][2], (bf16)acc[i][j][3]};
        *(bf16x4*)&Vt[((size_t)(b * 8 + kh) * 64 + d) * 2048 + s] = ov;
      }
  }
}

// ---------------------------------------------------------------------------
// Output projection GEMM (r7 body). XCD swizzle: 512 = 8*64; XCD c gets
// 2 bn x 32 bm -> 1MB B L2-resident.
// ---------------------------------------------------------------------------
__global__ __launch_bounds__(256, 2) void gemm_bt(const bf16* __restrict__ A,
                                                  const bf16* __restrict__ Bw,
                                                  float* __restrict__ C) {
  const int K = 2048, N = 2048;
  __shared__ bf16 As[3][128][32];
  const int t = threadIdx.x;
  const int wave = t >> 6, lane = t & 63, qd = lane >> 4, ln = lane & 15;
  const int wm = (wave >> 1) * 64;
  const int wn = (wave & 1) * 64;
  const int wg = blockIdx.x;
  const int swz = (wg & 7) * 64 + (wg >> 3);
  const size_t bn = (size_t)(swz >> 5) * 128;  // 0..15 cols blocks
  const size_t bm = (size_t)(swz & 31) * 128;  // 0..31 row blocks

  const bf16* Ab = A + bm * (size_t)K;
  const int n0 = (int)(bn >> 6) + (wn >> 6);
  const char* Bb = (const char*)Bw + (size_t)n0 * 262144 + (size_t)lane * 16;

  auto stage = [&](int tk, int slot) {
#pragma unroll
    for (int sub = 0; sub < 2; sub++) {
      int e = sub * 256 + t;
      int ro = e >> 2, gs = (e & 3) ^ ((ro >> 1) & 3);
      load_lds16(Ab + (size_t)ro * K + tk * 32 + gs * 8,
                 (char*)As + slot * 8192 + sub * 4096 + wave * 1024);
    }
  };

  f32x4 acc[4][4] = {};
  const int segoff = (qd ^ ((ln >> 1) & 3)) << 4;
  bf16x8 b0[4], b1[4];

#pragma unroll
  for (int j = 0; j < 4; j++)
    b0[j] = *(const bf16x8*)(Bb + (size_t)j * 1024);
  stage(0, 0);
  stage(1, 1);
  asm volatile("s_waitcnt vmcnt(2)" ::: "memory");
  __builtin_amdgcn_s_barrier();

  auto step = [&](int tk, bf16x8 (&cb)[4], bf16x8 (&nb)[4]) {
    if (tk < 62) stage(tk + 2, (tk + 2) % 3);
    if (tk < 63) {
#pragma unroll
      for (int j = 0; j < 4; j++)
        nb[j] = *(const bf16x8*)(Bb + (size_t)(tk + 1) * 4096 + j * 1024);
    }
    const char* Asl = (const char*)As + (tk % 3) * 8192;
    bf16x8 af[4];
#pragma unroll
    for (int i = 0; i < 4; i++)
      af[i] = *(const bf16x8*)(Asl + (wm + i * 16 + ln) * 64 + segoff);
    if (tk <= 61) asm volatile("s_waitcnt lgkmcnt(0) vmcnt(6)" ::: "memory");
    else if (tk == 62) asm volatile("s_waitcnt lgkmcnt(0) vmcnt(4)" ::: "memory");
    else asm volatile("s_waitcnt lgkmcnt(0) vmcnt(0)" ::: "memory");
    __builtin_amdgcn_sched_barrier(0);
    __builtin_amdgcn_s_setprio(1);
#pragma unroll
    for (int i = 0; i < 4; i++)
#pragma unroll
      for (int j = 0; j < 4; j++)
        acc[i][j] = __builtin_amdgcn_mfma_f32_16x16x32_bf16(af[i], cb[j],
                                                            acc[i][j], 0, 0, 0);
    __builtin_amdgcn_s_setprio(0);
    if (tk < 63) __builtin_amdgcn_s_barrier();
  };

  for (int tk = 0; tk < 64; tk += 2) {
    step(tk, b0, b1);
    step(tk + 1, b1, b0);
  }

#pragma unroll
  for (int i = 0; i < 4; i++)
#pragma unroll
    for (int j = 0; j < 4; j++)
#pragma unroll
      for (int r = 0; r < 4; r++) {
        size_t row = bm + wm + i * 16 + qd * 4 + r;
        size_t col = bn + wn + j * 16 + ln;
        C[row * N + col] = acc[i][j][r];
      }
}

// ---------------------------------------------------------------------------
// Flash attention (r5/r7 body, verified). XCD swizzle on bh: XCD c gets
// bh {8c..8c+7} = one batch x 2 KV-heads -> its 2MB of K+V stays L2-resident
// across all 16 q-tile groups (KV external traffic 278MB -> ~8MB).
// Q:(B,32,S,64)  K:(B,8,S,64)  Vt:(B,8,64,S)  ->  O:(B,S,32,64)
// ---------------------------------------------------------------------------
__global__ __launch_bounds__(256, 3) void attn_fwd(const bf16* __restrict__ Q,
                                                   const bf16* __restrict__ Kg,
                                                   const bf16* __restrict__ Vg,
                                                   bf16* __restrict__ O) {
  __shared__ bf16 Ks[2][64][64];  // 16 KB ring
  __shared__ bf16 Vs[2][64][64];  // 16 KB ring, [d][k]
  __shared__ bf16 Ps[128][64];    // [q][k], swizzled
  const int t = threadIdx.x;
  const int wave = t >> 6, lane = t & 63, qd = lane >> 4, ln = lane & 15;
  const int bid = blockIdx.x;
  const int qt = 15 - (bid >> 6);  // longest blocks dispatch first
  const int r0 = bid & 63;
  const int bh = (r0 & 7) * 8 + (r0 >> 3);  // XCD c -> bh 8c..8c+7
  const int b = bh >> 5, h = bh & 31, kh = h >> 2;
  const bf16* Qb = Q + ((size_t)(b * 32 + h) * 2048 + qt * 128) * 64;  // contiguous
  const bf16* Kb = Kg + (size_t)(b * 8 + kh) * 2048 * 64;              // contiguous
  const bf16* Vb = Vg + (size_t)(b * 8 + kh) * 64 * 2048;              // row stride 2048
  char* PsB = (char*)Ps;

  bf16x8 qf[2][2];
#pragma unroll
  for (int kk = 0; kk < 2; kk++)
#pragma unroll
    for (int mi = 0; mi < 2; mi++)
      qf[kk][mi] = *(const bf16x8*)(Qb + (wave * 32 + mi * 16 + ln) * 64 +
                                    (kk * 4 + qd) * 8);

  auto stageKV = [&](int kb, int buf) {
#pragma unroll
    for (int i = 0; i < 2; i++) {
      int e = i * 256 + t;
      int row = e >> 3, sg = (e & 7) ^ (row & 7);
      load_lds16(Kb + (size_t)(kb * 64 + row) * 64 + sg * 8,
                 (char*)Ks + buf * 8192 + i * 4096 + wave * 1024);
      load_lds16(Vb + (size_t)row * 2048 + kb * 64 + sg * 8,
                 (char*)Vs + buf * 8192 + i * 4096 + wave * 1024);
    }
  };

  f32x4 o_acc[4][2] = {};
  float l_st[2] = {0.f, 0.f};
  const int q0 = qt * 128 + wave * 32;
  const int nkb = 2 * qt + 2;

  stageKV(0, 0);
  __syncthreads();  // K0/V0 landed (vmcnt drain)

  for (int kb = 0; kb < nkb; kb++) {
    const int cur = kb & 1;
    if (kb + 1 < nkb) stageKV(kb + 1, cur ^ 1);
    const char* Ksl = (const char*)Ks + cur * 8192;
    const char* Vsl = (const char*)Vs + cur * 8192;

    // S^T = K*Q^T
    f32x4 s_acc[4][2] = {};
#pragma unroll
    for (int kk = 0; kk < 2; kk++) {
      bf16x8 ak[4];
#pragma unroll
      for (int j = 0; j < 4; j++) {
        int row = j * 16 + ln;
        int ph = (kk * 4 + qd) ^ (ln & 7);
        ak[j] = *(const bf16x8*)(Ksl + row * 128 + ph * 16);
      }
#pragma unroll
      for (int j = 0; j < 4; j++)
#pragma unroll
        for (int mi = 0; mi < 2; mi++)
          s_acc[j][mi] = __builtin_amdgcn_mfma_f32_16x16x32_bf16(
              ak[j], qf[kk][mi], s_acc[j][mi], 0, 0, 0);
    }

    // fixed-point softmax: p = 2^(s-16); masked -> exact 0
    auto smax = [&](auto maskc) {
      constexpr bool MASK = decltype(maskc)::value;
#pragma unroll
      for (int mi = 0; mi < 2; mi++) {
        const int qv = q0 + mi * 16 + ln;
        const int prow = wave * 32 + mi * 16 + ln;
        float rs = 0.f;
#pragma unroll
        for (int j = 0; j < 4; j++) {
          bf16x4 pk;
#pragma unroll
          for (int r = 0; r < 4; r++) {
            float s = s_acc[j][mi][r];
            if (MASK) {
              int k_glob = kb * 64 + j * 16 + qd * 4 + r;
              if (k_glob > qv) s = -1e5f;
            }
            float pv = exp2_fast(s - 16.f);
            rs += pv;
            pk[r] = (bf16)pv;
          }
          int ps = (j * 2 + (qd >> 1)) ^ (ln & 7);
          *(bf16x4*)(PsB + prow * 128 + ps * 16 + (qd & 1) * 8) = pk;
        }
        l_st[mi] += rs;
      }
    };
    if (kb * 64 + 63 > q0) smax(std::true_type{});
    else smax(std::false_type{});

    // O^T += V^T * P^T  (Ps wave-private; lgkmcnt orders write->read)
#pragma unroll
    for (int kk = 0; kk < 2; kk++) {
      bf16x8 av[4], bp[2];
#pragma unroll
      for (int dj = 0; dj < 4; dj++) {
        int row = dj * 16 + ln;
        int ph = (kk * 4 + qd) ^ (ln & 7);
        av[dj] = *(const bf16x8*)(Vsl + row * 128 + ph * 16);
      }
#pragma unroll
      for (int mi = 0; mi < 2; mi++) {
        int prow = wave * 32 + mi * 16 + ln;
        int ph = (kk * 4 + qd) ^ (ln & 7);
        bp[mi] = *(const bf16x8*)(PsB + prow * 128 + ph * 16);
      }
#pragma unroll
      for (int dj = 0; dj < 4; dj++)
#pragma unroll
        for (int mi = 0; mi < 2; mi++)
          o_acc[dj][mi] = __builtin_amdgcn_mfma_f32_16x16x32_bf16(
              av[dj], bp[mi], o_acc[dj][mi], 0, 0, 0);
    }

    __syncthreads();
  }

  // epilogue: reduce l across quads (each quad summed a disjoint k-subset)
#pragma unroll
  for (int mi = 0; mi < 2; mi++) {
    float lt = l_st[mi];
    lt += __shfl_xor(lt, 16);
    lt += __shfl_xor(lt, 32);
    float inv = 1.f / lt;
    int q_idx = qt * 128 + wave * 32 + mi * 16 + ln;
#pragma unroll
    for (int dj = 0; dj < 4; dj++) {
      bf16x4 ov;
#pragma unroll
      for (int r = 0; r < 4; r++) ov[r] = (bf16)(o_acc[dj][mi][r] * inv);
      *(bf16x4*)&O[((size_t)(b * 2048 + q_idx) * 32 + h) * 64 + dj * 16 + qd * 4] = ov;
    }
  }
}

// ---------------------------------------------------------------------------
extern "C" void kernel_launch(void* const* d_in, const int* in_sizes, int n_in,
                              void* d_out, int out_size, void* d_ws,
                              size_t ws_size, hipStream_t stream) {
  const float* x = (const float*)d_in[0];
  const float* fc = (const float*)d_in[1];
  const float* fs = (const float*)d_in[2];
  const float* wq = (const float*)d_in[3];
  const float* wk = (const float*)d_in[4];
  const float* wv = (const float*)d_in[5];
  const float* wo = (const float*)d_in[6];
  float* out = (float*)d_out;

  char* ws = (char*)d_ws;
  const size_t MB = (size_t)1 << 20;
  bf16* xb   = (bf16*)(ws + 0 * MB);   // 16 MB (4096,2048) row-major
  bf16* wqkv = (bf16*)(ws + 16 * MB);  // 12 MB fragment-shuffled
  bf16* wob  = (bf16*)(ws + 28 * MB);  // 8 MB fragment-shuffled
  bf16* Qro  = (bf16*)(ws + 36 * MB);  // 16 MB (B,32,S,64), roped*KAPPA
  bf16* Kro  = (bf16*)(ws + 52 * MB);  // 4 MB  (B,8,S,64), roped
  bf16* Vt   = (bf16*)(ws + 56 * MB);  // 4 MB  (B,8,64,S)
  bf16* Oa   = (bf16*)(ws + 60 * MB);  // 16 MB (B,S,32,64)

  dim3 blk(256);
  f2b_all<<<13312, blk, 0, stream>>>(x, wq, wk, wv, wo, xb, wqkv, wob);
  gemm_qkv<<<768, blk, 0, stream>>>(xb, wqkv, fc, fs, Qro, Kro, Vt);
  attn_fwd<<<1024, blk, 0, stream>>>(Qro, Kro, Vt, Oa);
  gemm_bt<<<512, blk, 0, stream>>>(Oa, wob, out);
}